// Round 17
// baseline (20.165 us; speedup 1.0000x reference)
//
#include <hip/hip_runtime.h>
#include <math.h>

#define T_SAMPLES 100
#define NB1 256            // hist blocks (1/CU, 16 waves each)
#define T1 1024
#define TF 1024            // final threads
#define NBINS 1024
#define RMIN -16.0f
#define BINW 0.03125f      // 32/1024 = 2^-5 exact
#define INV_BINW 32.0f
// u16 partial layout: region b's 1024 counts at u16 index PB16 + b*RS16
#define PB16 4096          // u16 index (byte 8192; clear of f32 minmax at bytes 256..2304)
#define RS16 1056          // 1024 + 32 u16 pad (64 B) -> region = 2112 B
// f32: min partials [64..320), max partials [320..576)
// footprint ~550 KB of ws. NO global zeroing needed: every word read is
// written earlier in the same call (poison-safe, replay-safe).

__global__ void __launch_bounds__(T1) cvar_hist(const float* __restrict__ pnl,
                                                int n, float* __restrict__ wsf) {
    __shared__ unsigned hist[NBINS];                      // 4 KB, count-only
    __shared__ float smin[T1 / 64], smax[T1 / 64];

    for (int i = threadIdx.x; i < NBINS; i += T1) hist[i] = 0u;
    __syncthreads();

    float lmin = INFINITY, lmax = -INFINITY;
    {
        int gtid = blockIdx.x * T1 + threadIdx.x;
        int stride = NB1 * T1;
        int n4 = n >> 2;
        const float4* p4 = (const float4*)pnl;
        for (int i = gtid; i < n4; i += stride) {
            float4 v = p4[i];
            float l[4] = {-v.x, -v.y, -v.z, -v.w};
            #pragma unroll
            for (int k = 0; k < 4; ++k) {
                lmin = fminf(lmin, l[k]);
                lmax = fmaxf(lmax, l[k]);
                float x = (l[k] - RMIN) * INV_BINW;
                int b = (int)fminf(fmaxf(x, 0.0f), 1023.0f);
                atomicAdd(&hist[b], 1u);
            }
        }
        for (int i = (n4 << 2) + gtid; i < n; i += stride) {
            float l = -pnl[i];
            lmin = fminf(lmin, l);
            lmax = fmaxf(lmax, l);
            float x = (l - RMIN) * INV_BINW;
            int b = (int)fminf(fmaxf(x, 0.0f), 1023.0f);
            atomicAdd(&hist[b], 1u);
        }
    }
    #pragma unroll
    for (int off = 32; off > 0; off >>= 1) {
        lmin = fminf(lmin, __shfl_down(lmin, off, 64));
        lmax = fmaxf(lmax, __shfl_down(lmax, off, 64));
    }
    int lane = threadIdx.x & 63, wid = threadIdx.x >> 6;
    if (lane == 0) { smin[wid] = lmin; smax[wid] = lmax; }
    __syncthreads();                                       // also fences hist atomics
    if (threadIdx.x == 0) {
        float a = smin[0], b = smax[0];
        for (int w = 1; w < T1 / 64; ++w) { a = fminf(a, smin[w]); b = fmaxf(b, smax[w]); }
        wsf[64 + blockIdx.x] = a;
        wsf[64 + NB1 + blockIdx.x] = b;
    }
    // u16 partial store (cnt per (block,bin) <= 7813 < 65536 always)
    unsigned short* reg = (unsigned short*)wsf + PB16 + (size_t)blockIdx.x * RS16;
    if (threadIdx.x < NBINS) reg[threadIdx.x] = (unsigned short)hist[threadIdx.x];
}

// Single block: read 540 KB partials (plain cached loads through the kernel
// boundary -- the proven-cheap handoff), minmax, suffix scan, evaluate, min.
__global__ void __launch_bounds__(TF) cvar_final(const float* __restrict__ wsf,
                                                 float* __restrict__ out, int n) {
    __shared__ unsigned cntH[2][NBINS];                   // 8 KB (two region-halves)
    __shared__ unsigned shist[NBINS];                     // 4 KB
    __shared__ double gC[NBINS], gK[NBINS];               // 16 KB
    __shared__ float smin[TF / 64], smax[TF / 64];
    __shared__ float s_tmin, s_tmax;
    __shared__ float sred[TF / 64];

    const int t = threadIdx.x;
    const int lane = t & 63, wid = t >> 6;

    // --- phase 1: column sums of the 256 x 1024 u16 partial matrix ---
    // thread t: bin-pair p = t&511 (bins 2p, 2p+1), region half h = t>>9.
    {
        const unsigned* part32 = (const unsigned*)((const unsigned short*)wsf + PB16);
        int p = t & 511, h = t >> 9;
        unsigned accLo = 0u, accHi = 0u;
        const int RS32 = RS16 / 2;                         // 528 u32 per region
        #pragma unroll 8
        for (int b = h * 128; b < h * 128 + 128; ++b) {
            unsigned v = part32[(size_t)b * RS32 + p];
            accLo += v & 0xFFFFu;
            accHi += v >> 16;
        }
        cntH[h][2 * p] = accLo;
        cntH[h][2 * p + 1] = accHi;
    }

    // --- min/max from the 2*NB1 f32 partials (also cached loads) ---
    {
        float a = (t < NB1) ? wsf[64 + t] : INFINITY;
        float b = (t < NB1) ? wsf[64 + NB1 + t] : -INFINITY;
        #pragma unroll
        for (int off = 32; off > 0; off >>= 1) {
            a = fminf(a, __shfl_down(a, off, 64));
            b = fmaxf(b, __shfl_down(b, off, 64));
        }
        if (lane == 0) { smin[wid] = a; smax[wid] = b; }
        __syncthreads();
        if (t == 0) {
            float mn = smin[0], mx = smax[0];
            for (int w = 1; w < TF / 64; ++w) { mn = fminf(mn, smin[w]); mx = fmaxf(mx, smax[w]); }
            s_tmin = mn;
            s_tmax = mx;
        }
    }
    __syncthreads();

    // --- combine halves; per-bin scan inputs ---
    {
        unsigned c = cntH[0][t] + cntH[1][t];
        shist[t] = c;
        gC[t] = (double)c;
        gK[t] = (double)c * (double)t;
    }
    __syncthreads();

    // --- inclusive suffix scan over 1024 bins (10 steps) ---
    for (int d = 1; d < NBINS; d <<= 1) {
        double c2 = 0.0, k2 = 0.0;
        if (t + d < NBINS) { c2 = gC[t + d]; k2 = gK[t + d]; }
        __syncthreads();
        gC[t] += c2; gK[t] += k2;
        __syncthreads();
    }

    const float t_min = s_tmin, t_max = s_tmax;
    const float dtf = (t_max - t_min) / (float)(T_SAMPLES - 1);

    float cvar = INFINITY;
    if (t < T_SAMPLES) {
        float tj = (t == T_SAMPLES - 1) ? t_max : t_min + (float)t * dtf;
        int kt = (int)fminf(fmaxf((tj - RMIN) * INV_BINW, 0.0f), 1023.0f);
        const double td = (double)tj, w = (double)BINW;

        double C = 0.0, K = 0.0;                           // suffix over bins >= kt+1
        if (kt + 1 < NBINS) { C = gC[kt + 1]; K = gK[kt + 1]; }
        // l ~ center_k = RMIN + w*(k+0.5)
        double S = C * ((double)RMIN + 0.5 * w - td) + w * K;
        double c = (double)shist[kt];                      // straddle bin, clamped
        S += fmax(0.0, c * ((double)RMIN + w * ((double)kt + 0.5) - td));
        cvar = (float)(td + S * (20.0 / (double)n));
    }
    #pragma unroll
    for (int off = 32; off > 0; off >>= 1)
        cvar = fminf(cvar, __shfl_down(cvar, off, 64));
    if (lane == 0) sred[wid] = cvar;
    __syncthreads();
    if (t == 0) {
        float m = sred[0];
        for (int w = 1; w < TF / 64; ++w) m = fminf(m, sred[w]);
        out[0] = m;
    }
}

extern "C" void kernel_launch(void* const* d_in, const int* in_sizes, int n_in,
                              void* d_out, int out_size, void* d_ws, size_t ws_size,
                              hipStream_t stream) {
    const float* pnl = (const float*)d_in[0];
    int n = in_sizes[0];
    float* wsf = (float*)d_ws;
    float* out = (float*)d_out;

    cvar_hist<<<NB1, T1, 0, stream>>>(pnl, n, wsf);
    cvar_final<<<1, TF, 0, stream>>>(wsf, out, n);
}

// Round 18
// 16.550 us; speedup vs baseline: 1.2184x; 1.2184x over previous
//
#include <hip/hip_runtime.h>
#include <math.h>

#define T_SAMPLES 100
#define NB1 256            // hist blocks (1/CU, 16 waves each)
#define T1 1024
#define TF 1024            // final threads
#define NBINS 512
#define RMIN -16.0f
#define BINW 0.0625f       // 32/512 = 2^-4 exact
#define INV_BINW 16.0f
// u16 partial layout: region b's 512 counts at u16 index PB16 + b*RS16
#define PB16 4096          // u16 index (byte 8192; clear of f32 minmax at bytes 256..2304)
#define RS16 544           // 512 + 32 u16 pad (64 B) -> region = 1088 B
// f32: min partials [64..320), max partials [320..576)
// footprint ~287 KB of ws. NO global zeroing needed: every word read is
// written earlier in the same call (poison-safe, replay-safe).

__global__ void __launch_bounds__(T1) cvar_hist(const float* __restrict__ pnl,
                                                int n, float* __restrict__ wsf) {
    __shared__ unsigned hist[NBINS];                      // 2 KB, count-only
    __shared__ float smin[T1 / 64], smax[T1 / 64];

    for (int i = threadIdx.x; i < NBINS; i += T1) hist[i] = 0u;
    __syncthreads();

    float lmin = INFINITY, lmax = -INFINITY;
    {
        int gtid = blockIdx.x * T1 + threadIdx.x;
        int stride = NB1 * T1;
        int n4 = n >> 2;
        const float4* p4 = (const float4*)pnl;
        for (int i = gtid; i < n4; i += stride) {
            float4 v = p4[i];
            float l[4] = {-v.x, -v.y, -v.z, -v.w};
            #pragma unroll
            for (int k = 0; k < 4; ++k) {
                lmin = fminf(lmin, l[k]);
                lmax = fmaxf(lmax, l[k]);
                float x = (l[k] - RMIN) * INV_BINW;
                int b = (int)fminf(fmaxf(x, 0.0f), 511.0f);
                atomicAdd(&hist[b], 1u);
            }
        }
        for (int i = (n4 << 2) + gtid; i < n; i += stride) {
            float l = -pnl[i];
            lmin = fminf(lmin, l);
            lmax = fmaxf(lmax, l);
            float x = (l - RMIN) * INV_BINW;
            int b = (int)fminf(fmaxf(x, 0.0f), 511.0f);
            atomicAdd(&hist[b], 1u);
        }
    }
    #pragma unroll
    for (int off = 32; off > 0; off >>= 1) {
        lmin = fminf(lmin, __shfl_down(lmin, off, 64));
        lmax = fmaxf(lmax, __shfl_down(lmax, off, 64));
    }
    int lane = threadIdx.x & 63, wid = threadIdx.x >> 6;
    if (lane == 0) { smin[wid] = lmin; smax[wid] = lmax; }
    __syncthreads();                                       // also fences hist atomics
    if (threadIdx.x == 0) {
        float a = smin[0], b = smax[0];
        for (int w = 1; w < T1 / 64; ++w) { a = fminf(a, smin[w]); b = fmaxf(b, smax[w]); }
        wsf[64 + blockIdx.x] = a;
        wsf[64 + NB1 + blockIdx.x] = b;
    }
    // u16 partial store: threads 0..255 pack 2 bins each -> 1 KB coalesced
    unsigned* reg32 = (unsigned*)((unsigned short*)wsf + PB16 + (size_t)blockIdx.x * RS16);
    if (threadIdx.x < NBINS / 2) {
        unsigned c0 = hist[2 * threadIdx.x];
        unsigned c1 = hist[2 * threadIdx.x + 1];
        reg32[threadIdx.x] = (c0 & 0xFFFFu) | (c1 << 16);
    }
}

// Single block: read 278 KB partials (plain cached loads through the kernel
// boundary), minmax, 9-step suffix scan over 512 bins, evaluate 100 t_j, min.
__global__ void __launch_bounds__(TF) cvar_final(const float* __restrict__ wsf,
                                                 float* __restrict__ out, int n) {
    __shared__ unsigned cntH[4][NBINS];                   // 8 KB (4 region-quarters)
    __shared__ unsigned shist[NBINS];                     // 2 KB
    __shared__ double gC[NBINS], gK[NBINS];               // 8 KB
    __shared__ float smin[TF / 64], smax[TF / 64];
    __shared__ float s_tmin, s_tmax;
    __shared__ float sred[TF / 64];

    const int t = threadIdx.x;
    const int lane = t & 63, wid = t >> 6;

    // --- phase 1: column sums of the 256 x 512 u16 partial matrix ---
    // thread t: bin-pair p = t&255 (bins 2p,2p+1), region quarter h = t>>8.
    {
        const unsigned* part32 = (const unsigned*)((const unsigned short*)wsf + PB16);
        int p = t & 255, h = t >> 8;
        unsigned accLo = 0u, accHi = 0u;
        const int RS32 = RS16 / 2;                         // 272 u32 per region
        #pragma unroll 8
        for (int b = h * 64; b < h * 64 + 64; ++b) {
            unsigned v = part32[(size_t)b * RS32 + p];
            accLo += v & 0xFFFFu;
            accHi += v >> 16;
        }
        cntH[h][2 * p] = accLo;
        cntH[h][2 * p + 1] = accHi;
    }

    // --- min/max from the 2*NB1 f32 partials (cached loads) ---
    {
        float a = (t < NB1) ? wsf[64 + t] : INFINITY;
        float b = (t < NB1) ? wsf[64 + NB1 + t] : -INFINITY;
        #pragma unroll
        for (int off = 32; off > 0; off >>= 1) {
            a = fminf(a, __shfl_down(a, off, 64));
            b = fmaxf(b, __shfl_down(b, off, 64));
        }
        if (lane == 0) { smin[wid] = a; smax[wid] = b; }
        __syncthreads();
        if (t == 0) {
            float mn = smin[0], mx = smax[0];
            for (int w = 1; w < TF / 64; ++w) { mn = fminf(mn, smin[w]); mx = fmaxf(mx, smax[w]); }
            s_tmin = mn;
            s_tmax = mx;
        }
    }
    __syncthreads();

    // --- combine quarters; per-bin scan inputs (threads 0..511) ---
    if (t < NBINS) {
        unsigned c = (cntH[0][t] + cntH[1][t]) + (cntH[2][t] + cntH[3][t]);
        shist[t] = c;
        gC[t] = (double)c;
        gK[t] = (double)c * (double)t;
    }
    __syncthreads();

    // --- inclusive suffix scan over 512 bins (9 steps; barriers uniform) ---
    for (int d = 1; d < NBINS; d <<= 1) {
        double c2 = 0.0, k2 = 0.0;
        if (t + d < NBINS) { c2 = gC[t + d]; k2 = gK[t + d]; }
        __syncthreads();
        if (t < NBINS) { gC[t] += c2; gK[t] += k2; }
        __syncthreads();
    }

    const float t_min = s_tmin, t_max = s_tmax;
    const float dtf = (t_max - t_min) / (float)(T_SAMPLES - 1);

    float cvar = INFINITY;
    if (t < T_SAMPLES) {
        float tj = (t == T_SAMPLES - 1) ? t_max : t_min + (float)t * dtf;
        int kt = (int)fminf(fmaxf((tj - RMIN) * INV_BINW, 0.0f), 511.0f);
        const double td = (double)tj, w = (double)BINW;

        double C = 0.0, K = 0.0;                           // suffix over bins >= kt+1
        if (kt + 1 < NBINS) { C = gC[kt + 1]; K = gK[kt + 1]; }
        // l ~ center_k = RMIN + w*(k+0.5)
        double S = C * ((double)RMIN + 0.5 * w - td) + w * K;
        double c = (double)shist[kt];                      // straddle bin, clamped
        S += fmax(0.0, c * ((double)RMIN + w * ((double)kt + 0.5) - td));
        cvar = (float)(td + S * (20.0 / (double)n));
    }
    #pragma unroll
    for (int off = 32; off > 0; off >>= 1)
        cvar = fminf(cvar, __shfl_down(cvar, off, 64));
    if (lane == 0) sred[wid] = cvar;
    __syncthreads();
    if (t == 0) {
        float m = sred[0];
        for (int w = 1; w < TF / 64; ++w) m = fminf(m, sred[w]);
        out[0] = m;
    }
}

extern "C" void kernel_launch(void* const* d_in, const int* in_sizes, int n_in,
                              void* d_out, int out_size, void* d_ws, size_t ws_size,
                              hipStream_t stream) {
    const float* pnl = (const float*)d_in[0];
    int n = in_sizes[0];
    float* wsf = (float*)d_ws;
    float* out = (float*)d_out;

    cvar_hist<<<NB1, T1, 0, stream>>>(pnl, n, wsf);
    cvar_final<<<1, TF, 0, stream>>>(wsf, out, n);
}

// Round 19
// 14.711 us; speedup vs baseline: 1.3708x; 1.1250x over previous
//
#include <hip/hip_runtime.h>
#include <math.h>

#define T_SAMPLES 100
#define NB1 256            // hist blocks (1/CU, 16 waves each)
#define T1 1024
#define TF 1024            // final threads
#define NBINS 256
#define RMIN -16.0f
#define BINW 0.125f        // 32/256 = 2^-3 exact
#define INV_BINW 8.0f
// u16 partial layout: region b's 256 counts at u16 index PB16 + b*RS16
#define RS16 288           // 256 + 32 u16 pad (64 B) -> region = 576 B
#define PB16 4096          // u16 index (byte 8192; clear of f32 minmax at bytes 256..2304)
// f32: min partials [64..320), max partials [320..576)
// footprint ~155 KB of ws. NO global zeroing needed: every word read is
// written earlier in the same call (poison-safe, replay-safe).

__global__ void __launch_bounds__(T1) cvar_hist(const float* __restrict__ pnl,
                                                int n, float* __restrict__ wsf) {
    __shared__ unsigned hist[NBINS];                      // 1 KB, count-only
    __shared__ float smin[T1 / 64], smax[T1 / 64];

    if (threadIdx.x < NBINS) hist[threadIdx.x] = 0u;
    __syncthreads();

    float lmin = INFINITY, lmax = -INFINITY;
    {
        int gtid = blockIdx.x * T1 + threadIdx.x;
        int stride = NB1 * T1;
        int n4 = n >> 2;
        const float4* p4 = (const float4*)pnl;
        for (int i = gtid; i < n4; i += stride) {
            float4 v = p4[i];
            float l[4] = {-v.x, -v.y, -v.z, -v.w};
            #pragma unroll
            for (int k = 0; k < 4; ++k) {
                lmin = fminf(lmin, l[k]);
                lmax = fmaxf(lmax, l[k]);
                float x = (l[k] - RMIN) * INV_BINW;
                int b = (int)fminf(fmaxf(x, 0.0f), 255.0f);
                atomicAdd(&hist[b], 1u);
            }
        }
        for (int i = (n4 << 2) + gtid; i < n; i += stride) {
            float l = -pnl[i];
            lmin = fminf(lmin, l);
            lmax = fmaxf(lmax, l);
            float x = (l - RMIN) * INV_BINW;
            int b = (int)fminf(fmaxf(x, 0.0f), 255.0f);
            atomicAdd(&hist[b], 1u);
        }
    }
    #pragma unroll
    for (int off = 32; off > 0; off >>= 1) {
        lmin = fminf(lmin, __shfl_down(lmin, off, 64));
        lmax = fmaxf(lmax, __shfl_down(lmax, off, 64));
    }
    int lane = threadIdx.x & 63, wid = threadIdx.x >> 6;
    if (lane == 0) { smin[wid] = lmin; smax[wid] = lmax; }
    __syncthreads();                                       // also fences hist atomics
    if (threadIdx.x == 0) {
        float a = smin[0], b = smax[0];
        for (int w = 1; w < T1 / 64; ++w) { a = fminf(a, smin[w]); b = fmaxf(b, smax[w]); }
        wsf[64 + blockIdx.x] = a;
        wsf[64 + NB1 + blockIdx.x] = b;
    }
    // u16 partial store: threads 0..127 pack 2 bins each -> 512 B coalesced
    unsigned* reg32 = (unsigned*)((unsigned short*)wsf + PB16 + (size_t)blockIdx.x * RS16);
    if (threadIdx.x < NBINS / 2) {
        unsigned c0 = hist[2 * threadIdx.x];
        unsigned c1 = hist[2 * threadIdx.x + 1];
        reg32[threadIdx.x] = (c0 & 0xFFFFu) | (c1 << 16);
    }
}

// Single block: read 147 KB partials (plain cached loads through the kernel
// boundary), minmax, 8-step suffix scan over 256 bins, evaluate 100 t_j, min.
__global__ void __launch_bounds__(TF) cvar_final(const float* __restrict__ wsf,
                                                 float* __restrict__ out, int n) {
    __shared__ unsigned cntH[8][NBINS];                   // 8 KB (8 region-eighths)
    __shared__ unsigned shist[NBINS];                     // 1 KB
    __shared__ double gC[NBINS], gK[NBINS];               // 4 KB
    __shared__ float smin[TF / 64], smax[TF / 64];
    __shared__ float s_tmin, s_tmax;
    __shared__ float sred[TF / 64];

    const int t = threadIdx.x;
    const int lane = t & 63, wid = t >> 6;

    // --- phase 1: column sums of the 256 x 256 u16 partial matrix ---
    // thread t: bin-pair p = t&127 (bins 2p,2p+1), region eighth h = t>>7.
    {
        const unsigned* part32 = (const unsigned*)((const unsigned short*)wsf + PB16);
        int p = t & 127, h = t >> 7;
        unsigned accLo = 0u, accHi = 0u;
        const int RS32 = RS16 / 2;                         // 144 u32 per region
        #pragma unroll 8
        for (int b = h * 32; b < h * 32 + 32; ++b) {
            unsigned v = part32[(size_t)b * RS32 + p];
            accLo += v & 0xFFFFu;
            accHi += v >> 16;
        }
        cntH[h][2 * p] = accLo;
        cntH[h][2 * p + 1] = accHi;
    }

    // --- min/max from the 2*NB1 f32 partials (cached loads) ---
    {
        float a = (t < NB1) ? wsf[64 + t] : INFINITY;
        float b = (t < NB1) ? wsf[64 + NB1 + t] : -INFINITY;
        #pragma unroll
        for (int off = 32; off > 0; off >>= 1) {
            a = fminf(a, __shfl_down(a, off, 64));
            b = fmaxf(b, __shfl_down(b, off, 64));
        }
        if (lane == 0) { smin[wid] = a; smax[wid] = b; }
        __syncthreads();
        if (t == 0) {
            float mn = smin[0], mx = smax[0];
            for (int w = 1; w < TF / 64; ++w) { mn = fminf(mn, smin[w]); mx = fmaxf(mx, smax[w]); }
            s_tmin = mn;
            s_tmax = mx;
        }
    }
    __syncthreads();

    // --- combine eighths; per-bin scan inputs (threads 0..255) ---
    if (t < NBINS) {
        unsigned c = ((cntH[0][t] + cntH[1][t]) + (cntH[2][t] + cntH[3][t]))
                   + ((cntH[4][t] + cntH[5][t]) + (cntH[6][t] + cntH[7][t]));
        shist[t] = c;
        gC[t] = (double)c;
        gK[t] = (double)c * (double)t;
    }
    __syncthreads();

    // --- inclusive suffix scan over 256 bins (8 steps; barriers uniform) ---
    for (int d = 1; d < NBINS; d <<= 1) {
        double c2 = 0.0, k2 = 0.0;
        if (t + d < NBINS) { c2 = gC[t + d]; k2 = gK[t + d]; }
        __syncthreads();
        if (t < NBINS) { gC[t] += c2; gK[t] += k2; }
        __syncthreads();
    }

    const float t_min = s_tmin, t_max = s_tmax;
    const float dtf = (t_max - t_min) / (float)(T_SAMPLES - 1);

    float cvar = INFINITY;
    if (t < T_SAMPLES) {
        float tj = (t == T_SAMPLES - 1) ? t_max : t_min + (float)t * dtf;
        int kt = (int)fminf(fmaxf((tj - RMIN) * INV_BINW, 0.0f), 255.0f);
        const double td = (double)tj, w = (double)BINW;

        double C = 0.0, K = 0.0;                           // suffix over bins >= kt+1
        if (kt + 1 < NBINS) { C = gC[kt + 1]; K = gK[kt + 1]; }
        // l ~ center_k = RMIN + w*(k+0.5)
        double S = C * ((double)RMIN + 0.5 * w - td) + w * K;
        double c = (double)shist[kt];                      // straddle bin, clamped
        S += fmax(0.0, c * ((double)RMIN + w * ((double)kt + 0.5) - td));
        cvar = (float)(td + S * (20.0 / (double)n));
    }
    #pragma unroll
    for (int off = 32; off > 0; off >>= 1)
        cvar = fminf(cvar, __shfl_down(cvar, off, 64));
    if (lane == 0) sred[wid] = cvar;
    __syncthreads();
    if (t == 0) {
        float m = sred[0];
        for (int w = 1; w < TF / 64; ++w) m = fminf(m, sred[w]);
        out[0] = m;
    }
}

extern "C" void kernel_launch(void* const* d_in, const int* in_sizes, int n_in,
                              void* d_out, int out_size, void* d_ws, size_t ws_size,
                              hipStream_t stream) {
    const float* pnl = (const float*)d_in[0];
    int n = in_sizes[0];
    float* wsf = (float*)d_ws;
    float* out = (float*)d_out;

    cvar_hist<<<NB1, T1, 0, stream>>>(pnl, n, wsf);
    cvar_final<<<1, TF, 0, stream>>>(wsf, out, n);
}

// Round 20
// 13.633 us; speedup vs baseline: 1.4792x; 1.0791x over previous
//
#include <hip/hip_runtime.h>
#include <math.h>

#define T_SAMPLES 100
#define NB1 256            // hist blocks (1/CU, 16 waves each)
#define T1 1024
#define TF 1024            // final threads
#define NBINS 128
#define RMIN -16.0f
#define BINW 0.25f         // 32/128 = 2^-2 exact
#define INV_BINW 4.0f
// u16 partial layout: region b's 128 counts at u16 index PB16 + b*RS16
#define RS16 160           // 128 + 32 u16 pad (64 B) -> region = 320 B
#define PB16 4096          // u16 index (byte 8192; clear of f32 minmax at bytes 256..2304)
// f32: min partials (of losses) [64..320), max partials [320..576)
// footprint ~90 KB of ws. NO global zeroing needed: every word read is
// written earlier in the same call (poison-safe, replay-safe).

__global__ void __launch_bounds__(T1) cvar_hist(const float* __restrict__ pnl,
                                                int n, float* __restrict__ wsf) {
    __shared__ unsigned h4[NBINS * 4];                    // 2 KB: 4 lane-keyed sub-hists
    __shared__ float smin[T1 / 64], smax[T1 / 64];

    for (int i = threadIdx.x; i < NBINS * 4; i += T1) h4[i] = 0u;
    __syncthreads();

    // track min/max in PNL domain (negate once at the end): lmin = -pmax etc.
    float pmin = INFINITY, pmax = -INFINITY;
    const int sub = threadIdx.x & 3;
    {
        int gtid = blockIdx.x * T1 + threadIdx.x;
        int stride = NB1 * T1;
        int n4 = n >> 2;
        const float4* p4 = (const float4*)pnl;
        for (int i = gtid; i < n4; i += stride) {
            float4 v = p4[i];
            pmin = fminf(pmin, fminf(fminf(v.x, v.y), fminf(v.z, v.w)));
            pmax = fmaxf(pmax, fmaxf(fmaxf(v.x, v.y), fmaxf(v.z, v.w)));
            float p[4] = {v.x, v.y, v.z, v.w};
            #pragma unroll
            for (int k = 0; k < 4; ++k) {
                // x = (l - RMIN)*INV with l = -p  ->  fma(p, -INV, -RMIN*INV)
                float x = fmaf(p[k], -INV_BINW, 64.0f);
                int b = (int)fminf(fmaxf(x, 0.0f), 127.0f);
                atomicAdd(&h4[(b << 2) | sub], 1u);
            }
        }
        for (int i = (n4 << 2) + gtid; i < n; i += stride) {
            float p = pnl[i];
            pmin = fminf(pmin, p);
            pmax = fmaxf(pmax, p);
            float x = fmaf(p, -INV_BINW, 64.0f);
            int b = (int)fminf(fmaxf(x, 0.0f), 127.0f);
            atomicAdd(&h4[(b << 2) | sub], 1u);
        }
    }
    #pragma unroll
    for (int off = 32; off > 0; off >>= 1) {
        pmin = fminf(pmin, __shfl_down(pmin, off, 64));
        pmax = fmaxf(pmax, __shfl_down(pmax, off, 64));
    }
    int lane = threadIdx.x & 63, wid = threadIdx.x >> 6;
    if (lane == 0) { smin[wid] = pmin; smax[wid] = pmax; }
    __syncthreads();                                       // also fences hist atomics
    if (threadIdx.x == 0) {
        float a = smin[0], b = smax[0];
        for (int w = 1; w < T1 / 64; ++w) { a = fminf(a, smin[w]); b = fmaxf(b, smax[w]); }
        wsf[64 + blockIdx.x] = -b;                         // loss min = -pnl max
        wsf[64 + NB1 + blockIdx.x] = -a;                   // loss max = -pnl min
    }
    // merge 4 subs + u16-pack: threads 0..63 handle 2 bins each -> 256 B store
    unsigned* reg32 = (unsigned*)((unsigned short*)wsf + PB16 + (size_t)blockIdx.x * RS16);
    if (threadIdx.x < NBINS / 2) {
        int b0 = 2 * threadIdx.x, b1 = 2 * threadIdx.x + 1;
        unsigned c0 = ((h4[(b0 << 2)] + h4[(b0 << 2) | 1]) +
                       (h4[(b0 << 2) | 2] + h4[(b0 << 2) | 3]));
        unsigned c1 = ((h4[(b1 << 2)] + h4[(b1 << 2) | 1]) +
                       (h4[(b1 << 2) | 2] + h4[(b1 << 2) | 3]));
        reg32[threadIdx.x] = (c0 & 0xFFFFu) | (c1 << 16);
    }
}

// Single block: read 80 KB partials (plain cached loads through the kernel
// boundary), minmax, 7-step suffix scan over 128 bins, evaluate 100 t_j, min.
__global__ void __launch_bounds__(TF) cvar_final(const float* __restrict__ wsf,
                                                 float* __restrict__ out, int n) {
    __shared__ unsigned cntH[16][NBINS];                  // 8 KB (16 region-groups)
    __shared__ unsigned shist[NBINS];                     // 512 B
    __shared__ double gC[NBINS], gK[NBINS];               // 2 KB
    __shared__ float smin[TF / 64], smax[TF / 64];
    __shared__ float s_tmin, s_tmax;
    __shared__ float sred[TF / 64];

    const int t = threadIdx.x;
    const int lane = t & 63, wid = t >> 6;

    // --- phase 1: column sums of the 256 x 128 u16 partial matrix ---
    // thread t: bin-pair p = t&63 (bins 2p,2p+1), region group h = t>>6 (16 regions each)
    {
        const unsigned* part32 = (const unsigned*)((const unsigned short*)wsf + PB16);
        int p = t & 63, h = t >> 6;
        unsigned accLo = 0u, accHi = 0u;
        const int RS32 = RS16 / 2;                         // 80 u32 per region
        #pragma unroll
        for (int b = h * 16; b < h * 16 + 16; ++b) {
            unsigned v = part32[(size_t)b * RS32 + p];
            accLo += v & 0xFFFFu;
            accHi += v >> 16;
        }
        cntH[h][2 * p] = accLo;
        cntH[h][2 * p + 1] = accHi;
    }

    // --- min/max from the 2*NB1 f32 partials (cached loads) ---
    {
        float a = (t < NB1) ? wsf[64 + t] : INFINITY;
        float b = (t < NB1) ? wsf[64 + NB1 + t] : -INFINITY;
        #pragma unroll
        for (int off = 32; off > 0; off >>= 1) {
            a = fminf(a, __shfl_down(a, off, 64));
            b = fmaxf(b, __shfl_down(b, off, 64));
        }
        if (lane == 0) { smin[wid] = a; smax[wid] = b; }
        __syncthreads();
        if (t == 0) {
            float mn = smin[0], mx = smax[0];
            for (int w = 1; w < TF / 64; ++w) { mn = fminf(mn, smin[w]); mx = fmaxf(mx, smax[w]); }
            s_tmin = mn;
            s_tmax = mx;
        }
    }
    __syncthreads();

    // --- combine 16 groups; per-bin scan inputs (threads 0..127) ---
    if (t < NBINS) {
        unsigned c = 0u;
        #pragma unroll
        for (int h = 0; h < 16; ++h) c += cntH[h][t];
        shist[t] = c;
        gC[t] = (double)c;
        gK[t] = (double)c * (double)t;
    }
    __syncthreads();

    // --- inclusive suffix scan over 128 bins (7 steps; barriers uniform) ---
    for (int d = 1; d < NBINS; d <<= 1) {
        double c2 = 0.0, k2 = 0.0;
        if (t + d < NBINS) { c2 = gC[t + d]; k2 = gK[t + d]; }
        __syncthreads();
        if (t < NBINS) { gC[t] += c2; gK[t] += k2; }
        __syncthreads();
    }

    const float t_min = s_tmin, t_max = s_tmax;
    const float dtf = (t_max - t_min) / (float)(T_SAMPLES - 1);

    float cvar = INFINITY;
    if (t < T_SAMPLES) {
        float tj = (t == T_SAMPLES - 1) ? t_max : t_min + (float)t * dtf;
        int kt = (int)fminf(fmaxf((tj - RMIN) * INV_BINW, 0.0f), 127.0f);
        const double td = (double)tj, w = (double)BINW;

        double C = 0.0, K = 0.0;                           // suffix over bins >= kt+1
        if (kt + 1 < NBINS) { C = gC[kt + 1]; K = gK[kt + 1]; }
        // l ~ center_k = RMIN + w*(k+0.5)
        double S = C * ((double)RMIN + 0.5 * w - td) + w * K;
        double c = (double)shist[kt];                      // straddle bin, clamped
        S += fmax(0.0, c * ((double)RMIN + w * ((double)kt + 0.5) - td));
        cvar = (float)(td + S * (20.0 / (double)n));
    }
    #pragma unroll
    for (int off = 32; off > 0; off >>= 1)
        cvar = fminf(cvar, __shfl_down(cvar, off, 64));
    if (lane == 0) sred[wid] = cvar;
    __syncthreads();
    if (t == 0) {
        float m = sred[0];
        for (int w = 1; w < TF / 64; ++w) m = fminf(m, sred[w]);
        out[0] = m;
    }
}

extern "C" void kernel_launch(void* const* d_in, const int* in_sizes, int n_in,
                              void* d_out, int out_size, void* d_ws, size_t ws_size,
                              hipStream_t stream) {
    const float* pnl = (const float*)d_in[0];
    int n = in_sizes[0];
    float* wsf = (float*)d_ws;
    float* out = (float*)d_out;

    cvar_hist<<<NB1, T1, 0, stream>>>(pnl, n, wsf);
    cvar_final<<<1, TF, 0, stream>>>(wsf, out, n);
}